// Round 2
// baseline (3207.595 us; speedup 1.0000x reference)
//
#include <hip/hip_runtime.h>

#define NB 256   // batch
#define NS 2048  // seq len
#define NI 128   // input dim
#define NH 256   // hidden dim

typedef _Float16 h2 __attribute__((ext_vector_type(2)));
typedef _Float16 h8 __attribute__((ext_vector_type(8)));

__device__ __forceinline__ float fdot2(h2 a, h2 b, float c) {
#if defined(__has_builtin)
#if __has_builtin(__builtin_amdgcn_fdot2)
  return __builtin_amdgcn_fdot2(a, b, c, false);
#else
  return c + (float)a[0] * (float)b[0] + (float)a[1] * (float)b[1];
#endif
#else
  return c + (float)a[0] * (float)b[0] + (float)a[1] * (float)b[1];
#endif
}

__global__ __launch_bounds__(256, 1) void elman_fused(
    const float* __restrict__ x_in,   // (B, S, I)
    const float* __restrict__ W_ih,   // (H, I)
    const float* __restrict__ W_hh,   // (H, H)
    const float* __restrict__ b_ih,   // (H)
    const float* __restrict__ b_hh,   // (H)
    float* __restrict__ out)          // (B, S, H)
{
  const int b = blockIdx.x;   // one batch row per workgroup
  const int t = threadIdx.x;  // one hidden unit per thread

  __shared__ h8 h_sm[NH / 8];       // 256 f16 = 512 B (current h)
  __shared__ h8 x_sm[2][NI / 8];    // double-buffered x row, 512 B

  // ---- Register-resident weight rows (f16-packed) ----
  h2 whh[NH / 2];  // 128 VGPRs
  {
    const float4* wr = (const float4*)(W_hh + (size_t)t * NH);
#pragma unroll
    for (int k = 0; k < NH / 4; ++k) {
      float4 w = wr[k];
      h2 p0 = {(_Float16)w.x, (_Float16)w.y};
      h2 p1 = {(_Float16)w.z, (_Float16)w.w};
      whh[2 * k] = p0;
      whh[2 * k + 1] = p1;
    }
  }
  h2 wih[NI / 2];  // 64 VGPRs
  {
    const float4* wr = (const float4*)(W_ih + (size_t)t * NI);
#pragma unroll
    for (int k = 0; k < NI / 4; ++k) {
      float4 w = wr[k];
      h2 p0 = {(_Float16)w.x, (_Float16)w.y};
      h2 p1 = {(_Float16)w.z, (_Float16)w.w};
      wih[2 * k] = p0;
      wih[2 * k + 1] = p1;
    }
  }
  const float bias = b_ih[t] + b_hh[t];

  // ---- Init: h0 = 0, stage x[s=0] ----
  ((_Float16*)h_sm)[t] = (_Float16)0.f;
  const float* xrow = x_in + (size_t)b * NS * NI;
  if (t < NI) ((_Float16*)x_sm[0])[t] = (_Float16)xrow[t];
  __syncthreads();

  float* orow = out + (size_t)b * NS * NH;

  for (int s = 0; s < NS; ++s) {
    // Prefetch next x row (hidden under the dot-product below).
    float xnext = 0.f;
    if (t < NI) {
      int sn = (s + 1 < NS) ? (s + 1) : s;
      xnext = xrow[(size_t)sn * NI + t];
    }

    // z = bias + W_hh[t,:]·h + W_ih[t,:]·x[s]
    float a0 = bias, a1 = 0.f, a2 = 0.f, a3 = 0.f;
    const h8* hp = h_sm;
    const h8* xp = x_sm[s & 1];
#pragma unroll
    for (int k = 0; k < NH / 8; ++k) {  // 32 broadcast b128 reads, 128 dot2
      h8 hv = hp[k];
      a0 = fdot2(whh[4 * k + 0], __builtin_shufflevector(hv, hv, 0, 1), a0);
      a1 = fdot2(whh[4 * k + 1], __builtin_shufflevector(hv, hv, 2, 3), a1);
      a2 = fdot2(whh[4 * k + 2], __builtin_shufflevector(hv, hv, 4, 5), a2);
      a3 = fdot2(whh[4 * k + 3], __builtin_shufflevector(hv, hv, 6, 7), a3);
    }
#pragma unroll
    for (int k = 0; k < NI / 8; ++k) {  // 16 reads, 64 dot2
      h8 xv = xp[k];
      a0 = fdot2(wih[4 * k + 0], __builtin_shufflevector(xv, xv, 0, 1), a0);
      a1 = fdot2(wih[4 * k + 1], __builtin_shufflevector(xv, xv, 2, 3), a1);
      a2 = fdot2(wih[4 * k + 2], __builtin_shufflevector(xv, xv, 4, 5), a2);
      a3 = fdot2(wih[4 * k + 3], __builtin_shufflevector(xv, xv, 6, 7), a3);
    }
    float z = (a0 + a1) + (a2 + a3);

    // tanh(z) = (e^{2z}-1)/(e^{2z}+1), clamped so exp can't overflow
    float zc = fminf(fmaxf(z, -30.f), 30.f);
    float e = __expf(2.f * zc);
    float hnew = (e - 1.f) / (e + 1.f);

    orow[(size_t)s * NH + t] = hnew;  // coalesced fp32 store

    __syncthreads();  // everyone done reading old h / x
    ((_Float16*)h_sm)[t] = (_Float16)hnew;
    if (t < NI) ((_Float16*)x_sm[(s + 1) & 1])[t] = (_Float16)xnext;
    __syncthreads();  // new h / x visible
  }
}

extern "C" void kernel_launch(void* const* d_in, const int* in_sizes, int n_in,
                              void* d_out, int out_size, void* d_ws, size_t ws_size,
                              hipStream_t stream) {
  const float* x_in = (const float*)d_in[0];
  const float* W_ih = (const float*)d_in[1];
  const float* W_hh = (const float*)d_in[2];
  const float* b_ih = (const float*)d_in[3];
  const float* b_hh = (const float*)d_in[4];
  float* out = (float*)d_out;

  elman_fused<<<NB, 256, 0, stream>>>(x_in, W_ih, W_hh, b_ih, b_hh, out);
}

// Round 5
// 2264.999 us; speedup vs baseline: 1.4162x; 1.4162x over previous
//
#include <hip/hip_runtime.h>

#define NB 256   // batch (= grid; one chain per CU)
#define NS 2048  // seq len
#define NI 128   // input dim
#define NH 256   // hidden dim

typedef _Float16 h2 __attribute__((ext_vector_type(2)));
typedef _Float16 h8 __attribute__((ext_vector_type(8)));

__device__ __forceinline__ float fdot2(h2 a, h2 b, float c) {
#if defined(__has_builtin)
#if __has_builtin(__builtin_amdgcn_fdot2)
  return __builtin_amdgcn_fdot2(a, b, c, false);
#else
  return c + (float)a[0] * (float)b[0] + (float)a[1] * (float)b[1];
#endif
#else
  return c + (float)a[0] * (float)b[0] + (float)a[1] * (float)b[1];
#endif
}

// 1024 threads: thread = (o = tid>>2, q = tid&3). o = output unit, q = K-quadrant.
// The 4 partial sums for output o live in lanes 4o..4o+3 -> shuffle reduce.
__global__ __launch_bounds__(1024, 4) void elman_splitk(
    const float* __restrict__ x_in,   // (B, S, I)
    const float* __restrict__ W_ih,   // (H, I)
    const float* __restrict__ W_hh,   // (H, H)
    const float* __restrict__ b_ih,   // (H)
    const float* __restrict__ b_hh,   // (H)
    float* __restrict__ out)          // (B, S, H)
{
  const int b   = blockIdx.x;
  const int tid = threadIdx.x;
  const int o   = tid >> 2;  // 0..255
  const int q   = tid & 3;   // 0..3

  // Quarter q of h at [q*72, q*72+64) f16; +8 f16 pad staggers the 4 broadcast
  // addresses onto disjoint bank groups (144B stride -> bank offset 4 per q).
  __shared__ __align__(16) _Float16 h_sm[4 * 72];       // 576 B
  __shared__ __align__(16) _Float16 x_sm[2][4 * 40];    // 2 x 320 B (quarter stride 80B)

  // ---- Register-resident quarter weight rows (f16-packed) ----
  h2 whh[32];  // W_hh[o][64q .. 64q+64)
  {
    const float4* wr = (const float4*)(W_hh + (size_t)o * NH + q * 64);
#pragma unroll
    for (int k = 0; k < 16; ++k) {
      float4 w = wr[k];
      whh[2 * k]     = h2{(_Float16)w.x, (_Float16)w.y};
      whh[2 * k + 1] = h2{(_Float16)w.z, (_Float16)w.w};
    }
  }
  h2 wih[16];  // W_ih[o][32q .. 32q+32)
  {
    const float4* wr = (const float4*)(W_ih + (size_t)o * NI + q * 32);
#pragma unroll
    for (int k = 0; k < 8; ++k) {
      float4 w = wr[k];
      wih[2 * k]     = h2{(_Float16)w.x, (_Float16)w.y};
      wih[2 * k + 1] = h2{(_Float16)w.z, (_Float16)w.w};
    }
  }
  const float bias = b_ih[o] + b_hh[o];

  // ---- Init: h0 = 0; stage x[0]; prefetch x[1] ----
  if (q == 0) h_sm[(o >> 6) * 72 + (o & 63)] = (_Float16)0.f;
  const float* xrow = x_in + (size_t)b * NS * NI;
  float xn = 0.f;
  if (tid < NI) {
    x_sm[0][(tid >> 5) * 40 + (tid & 31)] = (_Float16)xrow[tid];
    xn = xrow[NI + tid];  // row s=1
  }
  __syncthreads();

  float* orow = out + (size_t)b * NS * NH;

  for (int s = 0; s < NS; ++s) {
    const h8* hp = (const h8*)(h_sm + q * 72);
    const h8* xp = (const h8*)(x_sm[s & 1] + q * 40);

    float a0 = 0.f, a1 = 0.f, a2 = 0.f, a3 = 0.f;
#pragma unroll
    for (int k = 0; k < 8; ++k) {  // 8 broadcast b128, 32 dot2
      h8 v = hp[k];
      a0 = fdot2(whh[4 * k + 0], __builtin_shufflevector(v, v, 0, 1), a0);
      a1 = fdot2(whh[4 * k + 1], __builtin_shufflevector(v, v, 2, 3), a1);
      a2 = fdot2(whh[4 * k + 2], __builtin_shufflevector(v, v, 4, 5), a2);
      a3 = fdot2(whh[4 * k + 3], __builtin_shufflevector(v, v, 6, 7), a3);
    }
#pragma unroll
    for (int k = 0; k < 4; ++k) {  // 4 broadcast b128, 16 dot2
      h8 v = xp[k];
      a0 = fdot2(wih[4 * k + 0], __builtin_shufflevector(v, v, 0, 1), a0);
      a1 = fdot2(wih[4 * k + 1], __builtin_shufflevector(v, v, 2, 3), a1);
      a2 = fdot2(wih[4 * k + 2], __builtin_shufflevector(v, v, 4, 5), a2);
      a3 = fdot2(wih[4 * k + 3], __builtin_shufflevector(v, v, 6, 7), a3);
    }
    float r = (a0 + a1) + (a2 + a3);
    // 4-lane butterfly: all 4 lanes end with the full K-sum.
    r += __shfl_xor(r, 1);
    r += __shfl_xor(r, 2);
    float z = bias + r;

    // tanh(z) = (e^{2z}-1)/(e^{2z}+1)
    float zc = fminf(fmaxf(z, -30.f), 30.f);
    float e = __expf(2.f * zc);
    float hnew = (e - 1.f) / (e + 1.f);

    if (q == 0) orow[(size_t)s * NH + o] = hnew;  // 16 lanes/wave, 64B contiguous

    __syncthreads();  // everyone done reading old h / x
    if (q == 0) h_sm[(o >> 6) * 72 + (o & 63)] = (_Float16)hnew;
    if (tid < NI) x_sm[(s + 1) & 1][(tid >> 5) * 40 + (tid & 31)] = (_Float16)xn;
    __syncthreads();  // new h / x visible

    if (tid < NI) {  // prefetch x[s+2]; consumed at end of step s+1
      int sn = (s + 2 < NS) ? (s + 2) : (NS - 1);
      xn = xrow[(size_t)sn * NI + tid];
    }
  }
}

extern "C" void kernel_launch(void* const* d_in, const int* in_sizes, int n_in,
                              void* d_out, int out_size, void* d_ws, size_t ws_size,
                              hipStream_t stream) {
  const float* x_in = (const float*)d_in[0];
  const float* W_ih = (const float*)d_in[1];
  const float* W_hh = (const float*)d_in[2];
  const float* b_ih = (const float*)d_in[3];
  const float* b_hh = (const float*)d_in[4];
  float* out = (float*)d_out;

  elman_splitk<<<NB, 1024, 0, stream>>>(x_in, W_ih, W_hh, b_ih, b_hh, out);
}

// Round 6
// 2201.167 us; speedup vs baseline: 1.4572x; 1.0290x over previous
//
#include <hip/hip_runtime.h>

#define NB 256            // batch = grid (one chain per CU)
#define NS 2048           // seq len
#define NI 128            // input dim
#define NH 256            // hidden dim
#define KTOT (NH + NI)    // 384 = K-extension [h | x]
#define NKT (KTOT / 32)   // 12 k-tiles of 32
#define NTPW 2            // n-tiles per wave (16 tiles / 8 waves)

typedef _Float16 h8v __attribute__((ext_vector_type(8)));
typedef float f4v __attribute__((ext_vector_type(4)));

// 512 threads = 8 waves. Wave w owns output tiles n = [32w, 32w+16) and
// [32w+16, 32w+32). A-operand rows are all identical (h replicated across the
// 16 M-rows) so only D row 0 (lanes 0-15, acc reg 0) is meaningful.
// A/B use the same k-slot map sigma(g,j) = g*8 + j per 32-k tile, so any HW
// k-permutation cancels; only the C/D map (col=lane&15, row=(lane>>4)*4+reg,
// m89-verified) must be exact.
__global__ __launch_bounds__(512, 2) void elman_mfma(
    const float* __restrict__ x_in,   // (B, S, I)
    const float* __restrict__ W_ih,   // (H, I)
    const float* __restrict__ W_hh,   // (H, H)
    const float* __restrict__ b_ih,   // (H)
    const float* __restrict__ b_hh,   // (H)
    float* __restrict__ out)          // (B, S, H)
{
  const int b    = blockIdx.x;
  const int tid  = threadIdx.x;
  const int wave = tid >> 6;
  const int lane = tid & 63;
  const int g    = lane >> 4;   // 16-lane group 0..3
  const int c    = lane & 15;   // column within tile

  __shared__ __align__(16) _Float16 A_sm[KTOT];  // [h(256) | x(128)] f16

  const int n0 = (wave * NTPW + 0) * 16 + c;
  const int n1 = (wave * NTPW + 1) * 16 + c;

  // ---- B fragments (W^T, f16), loaded once, register/AGPR resident ----
  // Fragment (t, kt): lane(g,c) reg j holds B[k = kt*32 + g*8 + j][n] = W[n][k].
  h8v Bf0[NKT], Bf1[NKT];
#pragma unroll
  for (int kt = 0; kt < NKT; ++kt) {
    const int k = kt * 32 + g * 8;
    const float* s0 = (k < NH) ? (W_hh + (size_t)n0 * NH + k)
                               : (W_ih + (size_t)n0 * NI + (k - NH));
    const float* s1 = (k < NH) ? (W_hh + (size_t)n1 * NH + k)
                               : (W_ih + (size_t)n1 * NI + (k - NH));
    h8v v0, v1;
#pragma unroll
    for (int j = 0; j < 8; ++j) { v0[j] = (_Float16)s0[j]; v1[j] = (_Float16)s1[j]; }
    Bf0[kt] = v0;
    Bf1[kt] = v1;
  }
  const float bias0 = b_ih[n0] + b_hh[n0];
  const float bias1 = b_ih[n1] + b_hh[n1];

  // ---- Init: h = 0, stage x[0] ----
  if (tid < NH) A_sm[tid] = (_Float16)0.f;
  const float* xrow = x_in + (size_t)b * NS * NI;
  if (tid < NI) A_sm[NH + tid] = (_Float16)xrow[tid];
  __syncthreads();

  float* orow = out + (size_t)b * NS * NH;

  for (int s = 0; s < NS; ++s) {
    // Broadcast A-fragment reads: lane reads 16B at k = kt*32 + g*8
    // (16 lanes per group share one address -> conflict-free).
    h8v a[NKT];
#pragma unroll
    for (int kt = 0; kt < NKT; ++kt)
      a[kt] = *(const h8v*)(A_sm + kt * 32 + g * 8);

    // Prefetch next x row under the MFMAs.
    float xn = 0.f;
    if (tid < NI) {
      int sn = (s + 1 < NS) ? (s + 1) : s;
      xn = xrow[(size_t)sn * NI + tid];
    }

    f4v acc0 = {0.f, 0.f, 0.f, 0.f};
    f4v acc1 = {0.f, 0.f, 0.f, 0.f};
#pragma unroll
    for (int kt = 0; kt < NKT; ++kt) {
      acc0 = __builtin_amdgcn_mfma_f32_16x16x32_f16(a[kt], Bf0[kt], acc0, 0, 0, 0);
      acc1 = __builtin_amdgcn_mfma_f32_16x16x32_f16(a[kt], Bf1[kt], acc1, 0, 0, 0);
    }

    // Row m=0 lives in lanes 0-15 (g==0), acc reg 0.
    float h0 = 0.f, h1 = 0.f;
    if (lane < 16) {
      float z0 = bias0 + acc0[0];
      float z1 = bias1 + acc1[0];
      z0 = fminf(fmaxf(z0, -30.f), 30.f);
      z1 = fminf(fmaxf(z1, -30.f), 30.f);
      float e0 = __expf(2.f * z0);
      float e1 = __expf(2.f * z1);
      h0 = (e0 - 1.f) / (e0 + 1.f);
      h1 = (e1 - 1.f) / (e1 + 1.f);
      orow[(size_t)s * NH + n0] = h0;
      orow[(size_t)s * NH + n1] = h1;
    }

    __syncthreads();  // all waves done reading A_sm for step s
    if (lane < 16) {
      A_sm[n0] = (_Float16)h0;
      A_sm[n1] = (_Float16)h1;
    }
    if (tid < NI) A_sm[NH + tid] = (_Float16)xn;
    __syncthreads();  // new h / x visible
  }
}

extern "C" void kernel_launch(void* const* d_in, const int* in_sizes, int n_in,
                              void* d_out, int out_size, void* d_ws, size_t ws_size,
                              hipStream_t stream) {
  const float* x_in = (const float*)d_in[0];
  const float* W_ih = (const float*)d_in[1];
  const float* W_hh = (const float*)d_in[2];
  const float* b_ih = (const float*)d_in[3];
  const float* b_hh = (const float*)d_in[4];
  float* out = (float*)d_out;

  elman_mfma<<<NB, 512, 0, stream>>>(x_in, W_ih, W_hh, b_ih, b_hh, out);
}